// Round 3
// baseline (451.928 us; speedup 1.0000x reference)
//
#include <hip/hip_runtime.h>

#define B_ROWS 4096
#define N_COLS 8192
#define BLOCK  256
#define VPT    (N_COLS / 4 / BLOCK)   // float4 loads per thread per input = 8

// Native clang vector type: __builtin_nontemporal_load requires a pointer to
// scalar/vector-of-scalar, not HIP's HIP_vector_type struct.
typedef float vfloat4 __attribute__((ext_vector_type(4)));

// R6 post-mortem: asymmetric caching (NT preds / cached labels) REGRESSED
// +13.7 us (247.0 -> 260.7): with the per-iteration 512 MiB poison fill
// churning L3, letting labels allocate on miss adds L3 fill/evict traffic.
// NT-on-both keeps L3 passive and is the empirical best. Kept.
//
// R7 (bench infra failed, no data) / R8: fuse the mean reduction into the
// row kernel via ticket/last-block. Eliminates the serialized 1-block
// mean_kernel dispatch (~5-8 us). R8 de-risk: ticket reset is a 1-thread
// kernel, NOT hipMemsetAsync -> kernel_launch contains only plain kernel
// launches (unambiguously graph-capture-safe). Workspace is re-poisoned
// between iterations, so the ticket must be reset every launch.
// Last block reproduces the old mean_kernel arithmetic bit-exactly (same
// load order, same shuffle tree) -> absmax 0.0, deterministic.

__global__ void zero_ticket_kernel(unsigned int* __restrict__ ticket)
{
    *ticket = 0u;
}

__global__ __launch_bounds__(BLOCK) void row_pearson_fused(
    const float* __restrict__ preds,
    const float* __restrict__ labels,
    float* __restrict__ row_loss,
    unsigned int* __restrict__ ticket,
    float* __restrict__ out)
{
    const int row = blockIdx.x;
    const int tid = threadIdx.x;

    const vfloat4* p4 = reinterpret_cast<const vfloat4*>(preds  + (size_t)row * N_COLS);
    const vfloat4* l4 = reinterpret_cast<const vfloat4*>(labels + (size_t)row * N_COLS);

    float sx = 0.f, sy = 0.f, sxy = 0.f, sxx = 0.f, syy = 0.f;

    #pragma unroll
    for (int i = 0; i < VPT; ++i) {
        const vfloat4 x = __builtin_nontemporal_load(p4 + tid + i * BLOCK); // preds: stream
        const vfloat4 y = __builtin_nontemporal_load(l4 + tid + i * BLOCK); // labels: stream
        sx  += x.x + x.y + x.z + x.w;
        sy  += y.x + y.y + y.z + y.w;
        sxy += x.x * y.x + x.y * y.y + x.z * y.z + x.w * y.w;
        sxx += x.x * x.x + x.y * x.y + x.z * x.z + x.w * x.w;
        syy += y.x * y.x + y.y * y.y + y.z * y.z + y.w * y.w;
    }

    // 64-lane wave reduction (wave = 64 on gfx950).
    #pragma unroll
    for (int off = 32; off > 0; off >>= 1) {
        sx  += __shfl_down(sx,  off);
        sy  += __shfl_down(sy,  off);
        sxy += __shfl_down(sxy, off);
        sxx += __shfl_down(sxx, off);
        syy += __shfl_down(syy, off);
    }

    __shared__ float smem[4][5];   // 4 waves per block
    __shared__ bool last_block;
    const int wave = tid >> 6;
    const int lane = tid & 63;
    if (lane == 0) {
        smem[wave][0] = sx;  smem[wave][1] = sy;  smem[wave][2] = sxy;
        smem[wave][3] = sxx; smem[wave][4] = syy;
    }
    __syncthreads();

    if (tid == 0) {
        float tx = 0.f, ty = 0.f, txy = 0.f, txx = 0.f, tyy = 0.f;
        #pragma unroll
        for (int w = 0; w < BLOCK / 64; ++w) {
            tx  += smem[w][0]; ty  += smem[w][1]; txy += smem[w][2];
            txx += smem[w][3]; tyy += smem[w][4];
        }
        const float Nf  = (float)N_COLS;
        const float num = Nf * txy - tx * ty;
        const float den = sqrtf((Nf * txx - tx * tx) * (Nf * tyy - ty * ty));
        row_loss[row] = 1.0f - num / den;

        __threadfence();                              // release row_loss (device scope)
        const unsigned int done = atomicAdd(ticket, 1u);
        last_block = (done == B_ROWS - 1);
    }
    __syncthreads();

    if (!last_block) return;

    // Last block: reduce all 4096 row losses. Bit-identical to the former
    // mean_kernel (same load order, same shuffle tree).
    __threadfence();                                  // acquire: invalidate stale caches
    float s = 0.f;
    #pragma unroll
    for (int i = 0; i < B_ROWS / BLOCK; ++i)
        s += row_loss[tid + i * BLOCK];

    #pragma unroll
    for (int off = 32; off > 0; off >>= 1)
        s += __shfl_down(s, off);

    __shared__ float msum[4];
    if (lane == 0) msum[wave] = s;
    __syncthreads();

    if (tid == 0)
        out[0] = (msum[0] + msum[1] + msum[2] + msum[3]) / (float)B_ROWS;
}

extern "C" void kernel_launch(void* const* d_in, const int* in_sizes, int n_in,
                              void* d_out, int out_size, void* d_ws, size_t ws_size,
                              hipStream_t stream) {
    const float* preds  = (const float*)d_in[0];
    const float* labels = (const float*)d_in[1];
    float* row_loss      = (float*)d_ws;                                   // 4096 floats
    unsigned int* ticket = (unsigned int*)((char*)d_ws + B_ROWS * sizeof(float));
    float* out           = (float*)d_out;

    zero_ticket_kernel<<<1, 1, 0, stream>>>(ticket);
    row_pearson_fused<<<B_ROWS, BLOCK, 0, stream>>>(preds, labels, row_loss, ticket, out);
}

// Round 4
// 246.480 us; speedup vs baseline: 1.8335x; 1.8335x over previous
//
#include <hip/hip_runtime.h>

#define B_ROWS 4096
#define N_COLS 8192
#define BLOCK  256
#define VPT    (N_COLS / 4 / BLOCK)   // float4 loads per thread per input = 8

// Native clang vector type: __builtin_nontemporal_load requires a pointer to
// scalar/vector-of-scalar, not HIP's HIP_vector_type struct.
typedef float vfloat4 __attribute__((ext_vector_type(4)));

// SESSION LEDGER (what's been measured on this problem):
//  - R0 baseline (this exact structure): 247.0 us total. Kernel absent from
//    top-5 (cutoff 77 us) -> row kernel < 77 us.
//  - R1 asymmetric caching (NT preds / cached labels): 260.7 (+13.7).
//    Letting labels allocate in L3 under poison-fill churn adds fill/evict
//    traffic. NT-both keeps L3 passive (probe+hit-serve). REVERTED.
//  - R3 fused last-block mean w/ per-block __threadfence(): 451.9. The row
//    kernel ITSELF measured 247 us (545 GB/s, VALU 3.4%) -- 4096 per-block
//    device-scope fences (buffer_wbl2: full L2 writeback walks, not
//    address-ranged) serialize at TCC and throttle the fabric. REVERTED.
//  - Budget arithmetic from R3: dur_us = kernel + ~203 us of in-window
//    harness poison fills (2x 512 MiB @ 78 us @ 86% peak + small ones).
//    => R0's kernel+mean ~= 44 us vs ~43 us streaming roofline
//    (128 MiB HBM @ 6.3 TB/s overlapped/serial with 128 MiB L3 hits).
//    The kernel term is AT the roofline; the rest is harness-fixed.
__global__ __launch_bounds__(BLOCK) void row_pearson_kernel(
    const float* __restrict__ preds,
    const float* __restrict__ labels,
    float* __restrict__ row_loss)
{
    const int row = blockIdx.x;
    const int tid = threadIdx.x;

    const vfloat4* p4 = reinterpret_cast<const vfloat4*>(preds  + (size_t)row * N_COLS);
    const vfloat4* l4 = reinterpret_cast<const vfloat4*>(labels + (size_t)row * N_COLS);

    float sx = 0.f, sy = 0.f, sxy = 0.f, sxx = 0.f, syy = 0.f;

    #pragma unroll
    for (int i = 0; i < VPT; ++i) {
        const vfloat4 x = __builtin_nontemporal_load(p4 + tid + i * BLOCK);
        const vfloat4 y = __builtin_nontemporal_load(l4 + tid + i * BLOCK);
        sx  += x.x + x.y + x.z + x.w;
        sy  += y.x + y.y + y.z + y.w;
        sxy += x.x * y.x + x.y * y.y + x.z * y.z + x.w * y.w;
        sxx += x.x * x.x + x.y * x.y + x.z * x.z + x.w * x.w;
        syy += y.x * y.x + y.y * y.y + y.z * y.z + y.w * y.w;
    }

    // 64-lane wave reduction (wave = 64 on gfx950).
    #pragma unroll
    for (int off = 32; off > 0; off >>= 1) {
        sx  += __shfl_down(sx,  off);
        sy  += __shfl_down(sy,  off);
        sxy += __shfl_down(sxy, off);
        sxx += __shfl_down(sxx, off);
        syy += __shfl_down(syy, off);
    }

    __shared__ float smem[4][5];   // 4 waves per block
    const int wave = tid >> 6;
    const int lane = tid & 63;
    if (lane == 0) {
        smem[wave][0] = sx;  smem[wave][1] = sy;  smem[wave][2] = sxy;
        smem[wave][3] = sxx; smem[wave][4] = syy;
    }
    __syncthreads();

    if (tid == 0) {
        float tx = 0.f, ty = 0.f, txy = 0.f, txx = 0.f, tyy = 0.f;
        #pragma unroll
        for (int w = 0; w < BLOCK / 64; ++w) {
            tx  += smem[w][0]; ty  += smem[w][1]; txy += smem[w][2];
            txx += smem[w][3]; tyy += smem[w][4];
        }
        const float Nf  = (float)N_COLS;
        const float num = Nf * txy - tx * ty;
        const float den = sqrtf((Nf * txx - tx * tx) * (Nf * tyy - ty * ty));
        row_loss[row] = 1.0f - num / den;
    }
}

// Reduce 4096 per-row losses to the mean. Single block.
__global__ __launch_bounds__(BLOCK) void mean_kernel(
    const float* __restrict__ row_loss,
    float* __restrict__ out)
{
    const int tid = threadIdx.x;

    float s = 0.f;
    #pragma unroll
    for (int i = 0; i < B_ROWS / BLOCK; ++i)
        s += row_loss[tid + i * BLOCK];

    #pragma unroll
    for (int off = 32; off > 0; off >>= 1)
        s += __shfl_down(s, off);

    __shared__ float smem[4];
    const int wave = tid >> 6;
    const int lane = tid & 63;
    if (lane == 0) smem[wave] = s;
    __syncthreads();

    if (tid == 0) {
        float t = smem[0] + smem[1] + smem[2] + smem[3];
        out[0] = t / (float)B_ROWS;
    }
}

extern "C" void kernel_launch(void* const* d_in, const int* in_sizes, int n_in,
                              void* d_out, int out_size, void* d_ws, size_t ws_size,
                              hipStream_t stream) {
    const float* preds  = (const float*)d_in[0];
    const float* labels = (const float*)d_in[1];
    float* row_loss = (float*)d_ws;      // 4096 floats of scratch
    float* out      = (float*)d_out;

    row_pearson_kernel<<<B_ROWS, BLOCK, 0, stream>>>(preds, labels, row_loss);
    mean_kernel<<<1, BLOCK, 0, stream>>>(row_loss, out);
}